// Round 3
// baseline (145.706 us; speedup 1.0000x reference)
//
#include <hip/hip_runtime.h>
#include <hip/hip_bf16.h>
#include <stdint.h>

#define N2 8192
#define D 256
#define DB 512          // bytes per bf16 row
#define BLK_ROWS 512    // rows per block (8 waves x 64)
#define WAVE_ROWS 64
#define CHUNK 32        // cols staged per iteration
#define JSPLIT 16
#define COLS_PER_BLOCK (N2 / JSPLIT)              // 512
#define CHUNKS_PER_BLOCK (COLS_PER_BLOCK / CHUNK) // 16
#define NBLOCKS (16 * JSPLIT)                     // 256 = 1 per CU
#define SWZ(r, b) ((b) ^ (((r) & 7) << 4))

using short8 = __attribute__((ext_vector_type(8))) short;
using f32x4  = __attribute__((ext_vector_type(4))) float;

typedef __attribute__((address_space(1))) const char gchar_t;
typedef __attribute__((address_space(3))) char       lchar_t;

__device__ inline unsigned short f2bf(float x) {
    union { float f; uint32_t u; } a; a.f = x;
    uint32_t r = (a.u + 0x7fff + ((a.u >> 16) & 1)) >> 16;  // RNE
    return (unsigned short)r;
}

// ---------------- kernel 1: interleave + L2-normalize + bf16 ----------------
__global__ void knorm(const float* __restrict__ z1, const float* __restrict__ z2,
                      unsigned short* __restrict__ Zb, float* __restrict__ den,
                      int* __restrict__ counter) {
    int tid  = threadIdx.x;
    int lane = tid & 63;
    int w    = tid >> 6;
    int row  = blockIdx.x * 4 + w;          // 0..8191
    const float* src = (row & 1) ? z2 : z1;
    int srow = row >> 1;
    float4 v = reinterpret_cast<const float4*>(src + (size_t)srow * D)[lane];
    float ss = v.x*v.x + v.y*v.y + v.z*v.z + v.w*v.w;
    #pragma unroll
    for (int off = 1; off < 64; off <<= 1) ss += __shfl_xor(ss, off);
    float inv = rsqrtf(ss);
    ushort4 o;
    o.x = f2bf(v.x * inv); o.y = f2bf(v.y * inv);
    o.z = f2bf(v.z * inv); o.w = f2bf(v.w * inv);
    *reinterpret_cast<ushort4*>(Zb + (size_t)row * D + lane * 4) = o;

    int gid = blockIdx.x * blockDim.x + tid;
    if (gid < N2) den[gid] = 0.f;
    if (gid == 0) *counter = 0;
}

// ------- kernel 2: S rowsums (excl diag) + positive dots + final loss -------
__launch_bounds__(512, 2)
__global__ void kmain(const unsigned short* __restrict__ Zb,
                      float* __restrict__ den, float* __restrict__ pos,
                      int* __restrict__ counter, float* __restrict__ out) {
    __shared__ char tile[2][CHUNK * DB];     // 2 x 16 KB double buffer
    int tid  = threadIdx.x;
    int lane = tid & 63;
    int w    = tid >> 6;                     // 0..7
    int bid  = blockIdx.x;
    int rb   = bid & 15;                     // 16 row-blocks
    int js   = bid >> 4;                     // 16 column splits
    int Rw   = rb * BLK_ROWS + w * WAVE_ROWS;
    int Cbase = js * COLS_PER_BLOCK;
    int l15 = lane & 15, g = lane >> 4;

    const char* Zc = reinterpret_cast<const char*>(Zb);

    // staging geometry: wave stages 4 rows via 2 DMA ops; pre-swizzled source
    int soff[2];
    #pragma unroll
    for (int k = 0; k < 2; ++k) {
        int r = w*4 + k*2 + (lane >> 5);     // local row 0..31
        int y = (lane & 31) * 16;
        soff[k] = r * DB + SWZ(r, y);
    }
    const size_t cb0 = (size_t)Cbase * DB;

    #define STAGE(bf, coff)                                                          \
        __builtin_amdgcn_global_load_lds(                                            \
            (gchar_t*)(Zc + (coff) + soff[0]),                                       \
            (lchar_t*)(&tile[bf][(w*4 + 0) * DB]), 16, 0, 0);                        \
        __builtin_amdgcn_global_load_lds(                                            \
            (gchar_t*)(Zc + (coff) + soff[1]),                                       \
            (lchar_t*)(&tile[bf][(w*4 + 2) * DB]), 16, 0, 0);

    STAGE(0, cb0);                           // prologue: chunk 0 -> buf 0

    // A fragments: 4 m-frags x 8 k-steps, register-resident (128 VGPR)
    short8 A[4][8];
    #pragma unroll
    for (int mf = 0; mf < 4; ++mf) {
        const char* rowp = Zc + (size_t)(Rw + mf*16 + l15) * DB + g*16;
        #pragma unroll
        for (int s = 0; s < 8; ++s)
            A[mf][s] = *reinterpret_cast<const short8*>(rowp + s*64);
    }

    float rsum[4][4];
    #pragma unroll
    for (int mf = 0; mf < 4; ++mf)
        #pragma unroll
        for (int r = 0; r < 4; ++r) rsum[mf][r] = 0.f;

    __syncthreads();                         // buf0 staged (drains vmcnt)
    int buf = 0;

    for (int c = 0; c < CHUNKS_PER_BLOCK; ++c) {
        if (c + 1 < CHUNKS_PER_BLOCK)        // overwrites buffer whose readers
            STAGE(buf ^ 1, cb0 + (size_t)(c + 1) * CHUNK * DB);  // flushed last iter

        f32x4 acc[4][2];
        #pragma unroll
        for (int mf = 0; mf < 4; ++mf)
            #pragma unroll
            for (int nf = 0; nf < 2; ++nf) acc[mf][nf] = (f32x4){0.f,0.f,0.f,0.f};

        #pragma unroll
        for (int s = 0; s < 8; ++s) {
            int cb = s*64 + g*16;
            int r0 = l15, r1 = 16 + l15;
            short8 B0 = *reinterpret_cast<const short8*>(&tile[buf][r0 * DB + SWZ(r0, cb)]);
            short8 B1 = *reinterpret_cast<const short8*>(&tile[buf][r1 * DB + SWZ(r1, cb)]);
            #pragma unroll
            for (int mf = 0; mf < 4; ++mf) {
                acc[mf][0] = __builtin_amdgcn_mfma_f32_16x16x32_bf16(A[mf][s], B0, acc[mf][0], 0, 0, 0);
                acc[mf][1] = __builtin_amdgcn_mfma_f32_16x16x32_bf16(A[mf][s], B1, acc[mf][1], 0, 0, 0);
            }
        }

        int C0 = Cbase + c * CHUNK;
        #pragma unroll
        for (int mf = 0; mf < 4; ++mf) {
            int Rt = Rw + mf * 16;
            #pragma unroll
            for (int nf = 0; nf < 2; ++nf) {
                int Ct = C0 + nf * 16;
                bool dg = (Ct == Rt);
                #pragma unroll
                for (int r = 0; r < 4; ++r) {
                    float v = acc[mf][nf][r];            // C: row g*4+r, col l15
                    float e = exp2f(v * 2.885390081777927f);  // exp(2v)
                    if (dg) {
                        int rl = g * 4 + r;
                        if (l15 == rl) e = 0.f;                 // exclude diagonal
                        if (l15 == (rl ^ 1)) pos[Rt + rl] = v;  // positive dot
                    }
                    rsum[mf][r] += e;
                }
            }
        }
        __syncthreads();   // drains vmcnt+lgkmcnt, then barrier: next STAGE safe
        buf ^= 1;
    }

    // reduce rowsums across the 16 cols held per lane-group, then accumulate
    #pragma unroll
    for (int mf = 0; mf < 4; ++mf) {
        #pragma unroll
        for (int r = 0; r < 4; ++r) {
            float v = rsum[mf][r];
            v += __shfl_xor(v, 1); v += __shfl_xor(v, 2);
            v += __shfl_xor(v, 4); v += __shfl_xor(v, 8);
            if (l15 == 0) atomicAdd(&den[Rw + mf*16 + g*4 + r], v);
        }
    }

    // ---- last block computes the final loss ----
    __shared__ int  amLast;
    __shared__ float red[8];
    __threadfence();                         // den/pos visible device-wide
    __syncthreads();
    if (tid == 0) amLast = (atomicAdd(counter, 1) == NBLOCKS - 1);
    __syncthreads();
    if (!amLast) return;
    __threadfence();                         // acquire

    float s = 0.f;
    for (int i = tid; i < N2; i += 512) {
        float d = __hip_atomic_load(&den[i], __ATOMIC_RELAXED, __HIP_MEMORY_SCOPE_AGENT);
        float p = __hip_atomic_load(&pos[i], __ATOMIC_RELAXED, __HIP_MEMORY_SCOPE_AGENT);
        s += logf(d + 1e-8f) - 2.f * p;
    }
    #pragma unroll
    for (int off = 1; off < 64; off <<= 1) s += __shfl_xor(s, off);
    if (lane == 0) red[w] = s;
    __syncthreads();
    if (tid == 0) {
        float t = 0.f;
        #pragma unroll
        for (int i = 0; i < 8; ++i) t += red[i];
        out[0] = t * (1.f / (float)N2);
    }
}

extern "C" void kernel_launch(void* const* d_in, const int* in_sizes, int n_in,
                              void* d_out, int out_size, void* d_ws, size_t ws_size,
                              hipStream_t stream) {
    const float* z1 = (const float*)d_in[0];
    const float* z2 = (const float*)d_in[1];
    char* ws = (char*)d_ws;
    unsigned short* Zb = (unsigned short*)ws;                       // 4 MB bf16 Z
    float* den = (float*)(ws + (size_t)N2 * DB);                    // 32 KB
    float* pos = (float*)(ws + (size_t)N2 * DB + (size_t)N2 * 4);   // 32 KB
    int* counter = (int*)(ws + (size_t)N2 * DB + (size_t)N2 * 8);

    knorm<<<N2 / 4, 256, 0, stream>>>(z1, z2, Zb, den, counter);
    kmain<<<NBLOCKS, 512, 0, stream>>>(Zb, den, pos, counter, (float*)d_out);
}

// Round 4
// 141.866 us; speedup vs baseline: 1.0271x; 1.0271x over previous
//
#include <hip/hip_runtime.h>
#include <hip/hip_bf16.h>
#include <stdint.h>

#define N2 8192
#define D 256
#define DB 512          // bytes per bf16 row
#define BLK_ROWS 256    // rows per block (4 waves x 64)
#define WAVE_ROWS 64
#define CHUNK 32        // cols staged per iteration
#define JSPLIT 16
#define COLS_PER_BLOCK (N2 / JSPLIT)              // 512
#define CHUNKS_PER_BLOCK (COLS_PER_BLOCK / CHUNK) // 16
#define NBLOCKS (32 * JSPLIT)                     // 512 = 2 per CU
#define SWZ(r, b) ((b) ^ (((r) & 7) << 4))

using short8 = __attribute__((ext_vector_type(8))) short;
using f32x4  = __attribute__((ext_vector_type(4))) float;

typedef __attribute__((address_space(1))) const char gchar_t;
typedef __attribute__((address_space(3))) char       lchar_t;

__device__ inline unsigned short f2bf(float x) {
    union { float f; uint32_t u; } a; a.f = x;
    uint32_t r = (a.u + 0x7fff + ((a.u >> 16) & 1)) >> 16;  // RNE
    return (unsigned short)r;
}

// ---------------- kernel 1: interleave + L2-normalize + bf16 ----------------
__global__ void knorm(const float* __restrict__ z1, const float* __restrict__ z2,
                      unsigned short* __restrict__ Zb, float* __restrict__ den,
                      int* __restrict__ counter) {
    int tid  = threadIdx.x;
    int lane = tid & 63;
    int w    = tid >> 6;
    int row  = blockIdx.x * 4 + w;          // 0..8191
    const float* src = (row & 1) ? z2 : z1;
    int srow = row >> 1;
    float4 v = reinterpret_cast<const float4*>(src + (size_t)srow * D)[lane];
    float ss = v.x*v.x + v.y*v.y + v.z*v.z + v.w*v.w;
    #pragma unroll
    for (int off = 1; off < 64; off <<= 1) ss += __shfl_xor(ss, off);
    float inv = rsqrtf(ss);
    ushort4 o;
    o.x = f2bf(v.x * inv); o.y = f2bf(v.y * inv);
    o.z = f2bf(v.z * inv); o.w = f2bf(v.w * inv);
    *reinterpret_cast<ushort4*>(Zb + (size_t)row * D + lane * 4) = o;

    int gid = blockIdx.x * blockDim.x + tid;
    if (gid < N2) den[gid] = 0.f;
    if (gid == 0) *counter = 0;
}

// ------- kernel 2: S rowsums (excl diag) + positive dots + final loss -------
__launch_bounds__(256, 2)
__global__ void kmain(const unsigned short* __restrict__ Zb,
                      float* __restrict__ den, float* __restrict__ pos,
                      int* __restrict__ counter, float* __restrict__ out) {
    __shared__ char tile[2][CHUNK * DB];     // 2 x 16 KB double buffer
    int tid  = threadIdx.x;
    int lane = tid & 63;
    int w    = tid >> 6;                     // 0..3
    int bid  = blockIdx.x;
    int rb   = bid & 31;                     // 32 row-blocks of 256 rows
    int js   = bid >> 5;                     // 16 column splits
    int Rw   = rb * BLK_ROWS + w * WAVE_ROWS;
    int Cbase = js * COLS_PER_BLOCK;
    int l15 = lane & 15, g = lane >> 4;

    const char* Zc = reinterpret_cast<const char*>(Zb);

    // staging geometry: each wave stages 8 rows via 4 DMA ops (2 rows each);
    // global source pre-swizzled so linear LDS dest yields swizzled layout.
    int soff[4];
    #pragma unroll
    for (int k = 0; k < 4; ++k) {
        int r = w*8 + k*2 + (lane >> 5);     // local row 0..31
        int y = (lane & 31) * 16;
        soff[k] = r * DB + SWZ(r, y);
    }
    const size_t cb0 = (size_t)Cbase * DB;

    #define STAGE(bf, coff)                                                          \
        _Pragma("unroll")                                                            \
        for (int k = 0; k < 4; ++k)                                                  \
            __builtin_amdgcn_global_load_lds(                                        \
                (gchar_t*)(Zc + (coff) + soff[k]),                                   \
                (lchar_t*)(&tile[bf][(w*8 + k*2) * DB]), 16, 0, 0);

    STAGE(0, cb0);                           // prologue: chunk 0 -> buf 0 (in flight)

    // A fragments: 4 m-frags x 8 k-steps, register-resident (128 VGPR)
    short8 A[4][8];
    #pragma unroll
    for (int mf = 0; mf < 4; ++mf) {
        const char* rowp = Zc + (size_t)(Rw + mf*16 + l15) * DB + g*16;
        #pragma unroll
        for (int s = 0; s < 8; ++s)
            A[mf][s] = *reinterpret_cast<const short8*>(rowp + s*64);
    }
    // Opaque fence: makes A values non-rematerializable so the allocator
    // MUST keep them in VGPRs instead of sinking the loads into the loop.
    #pragma unroll
    for (int mf = 0; mf < 4; ++mf)
        #pragma unroll
        for (int s = 0; s < 8; ++s)
            asm volatile("" : "+v"(A[mf][s]));

    float rsum[4][4];
    #pragma unroll
    for (int mf = 0; mf < 4; ++mf)
        #pragma unroll
        for (int r = 0; r < 4; ++r) rsum[mf][r] = 0.f;

    __syncthreads();                         // buf0 staged (drains vmcnt)
    int buf = 0;

    for (int c = 0; c < CHUNKS_PER_BLOCK; ++c) {
        if (c + 1 < CHUNKS_PER_BLOCK)        // readers of buf^1 flushed last iter
            STAGE(buf ^ 1, cb0 + (size_t)(c + 1) * CHUNK * DB);

        f32x4 acc[4][2];
        #pragma unroll
        for (int mf = 0; mf < 4; ++mf)
            #pragma unroll
            for (int nf = 0; nf < 2; ++nf) acc[mf][nf] = (f32x4){0.f,0.f,0.f,0.f};

        #pragma unroll
        for (int s = 0; s < 8; ++s) {
            int cb = s*64 + g*16;
            int r0 = l15, r1 = 16 + l15;
            short8 B0 = *reinterpret_cast<const short8*>(&tile[buf][r0 * DB + SWZ(r0, cb)]);
            short8 B1 = *reinterpret_cast<const short8*>(&tile[buf][r1 * DB + SWZ(r1, cb)]);
            #pragma unroll
            for (int mf = 0; mf < 4; ++mf) {
                acc[mf][0] = __builtin_amdgcn_mfma_f32_16x16x32_bf16(A[mf][s], B0, acc[mf][0], 0, 0, 0);
                acc[mf][1] = __builtin_amdgcn_mfma_f32_16x16x32_bf16(A[mf][s], B1, acc[mf][1], 0, 0, 0);
            }
        }

        int C0 = Cbase + c * CHUNK;
        #pragma unroll
        for (int mf = 0; mf < 4; ++mf) {
            int Rt = Rw + mf * 16;
            #pragma unroll
            for (int nf = 0; nf < 2; ++nf) {
                int Ct = C0 + nf * 16;
                bool dg = (Ct == Rt);
                #pragma unroll
                for (int r = 0; r < 4; ++r) {
                    float v = acc[mf][nf][r];            // C: row g*4+r, col l15
                    float e = exp2f(v * 2.885390081777927f);  // exp(2v)
                    if (dg) {
                        int rl = g * 4 + r;
                        if (l15 == rl) e = 0.f;                 // exclude diagonal
                        if (l15 == (rl ^ 1)) pos[Rt + rl] = v;  // positive dot
                    }
                    rsum[mf][r] += e;
                }
            }
        }
        __syncthreads();   // drains vmcnt+lgkmcnt then barrier: next STAGE safe
        buf ^= 1;
    }

    // reduce rowsums across the 16 cols held per lane-group, then accumulate
    #pragma unroll
    for (int mf = 0; mf < 4; ++mf) {
        #pragma unroll
        for (int r = 0; r < 4; ++r) {
            float v = rsum[mf][r];
            v += __shfl_xor(v, 1); v += __shfl_xor(v, 2);
            v += __shfl_xor(v, 4); v += __shfl_xor(v, 8);
            if (l15 == 0) atomicAdd(&den[Rw + mf*16 + g*4 + r], v);
        }
    }

    // ---- last block computes the final loss ----
    __shared__ int  amLast;
    __shared__ float red[4];
    __threadfence();                         // den/pos visible device-wide
    __syncthreads();
    if (tid == 0) amLast = (atomicAdd(counter, 1) == NBLOCKS - 1);
    __syncthreads();
    if (!amLast) return;
    __threadfence();                         // acquire

    float s = 0.f;
    for (int i = tid; i < N2; i += 256) {
        float d = __hip_atomic_load(&den[i], __ATOMIC_RELAXED, __HIP_MEMORY_SCOPE_AGENT);
        float p = __hip_atomic_load(&pos[i], __ATOMIC_RELAXED, __HIP_MEMORY_SCOPE_AGENT);
        s += logf(d + 1e-8f) - 2.f * p;
    }
    #pragma unroll
    for (int off = 1; off < 64; off <<= 1) s += __shfl_xor(s, off);
    if (lane == 0) red[w] = s;
    __syncthreads();
    if (tid == 0) {
        float t = 0.f;
        #pragma unroll
        for (int i = 0; i < 4; ++i) t += red[i];
        out[0] = t * (1.f / (float)N2);
    }
}

extern "C" void kernel_launch(void* const* d_in, const int* in_sizes, int n_in,
                              void* d_out, int out_size, void* d_ws, size_t ws_size,
                              hipStream_t stream) {
    const float* z1 = (const float*)d_in[0];
    const float* z2 = (const float*)d_in[1];
    char* ws = (char*)d_ws;
    unsigned short* Zb = (unsigned short*)ws;                       // 4 MB bf16 Z
    float* den = (float*)(ws + (size_t)N2 * DB);                    // 32 KB
    float* pos = (float*)(ws + (size_t)N2 * DB + (size_t)N2 * 4);   // 32 KB
    int* counter = (int*)(ws + (size_t)N2 * DB + (size_t)N2 * 8);

    knorm<<<N2 / 4, 256, 0, stream>>>(z1, z2, Zb, den, counter);
    kmain<<<NBLOCKS, 256, 0, stream>>>(Zb, den, pos, counter, (float*)d_out);
}

// Round 6
// 138.932 us; speedup vs baseline: 1.0488x; 1.0211x over previous
//
#include <hip/hip_runtime.h>
#include <hip/hip_bf16.h>
#include <stdint.h>

#define N2 8192
#define D 256
#define DB 512          // bytes per bf16 row
#define BLK_ROWS 256    // rows per block (4 waves x 64)
#define WAVE_ROWS 64
#define CHUNK 32        // cols staged per iteration
#define JSPLIT 16
#define COLS_PER_BLOCK (N2 / JSPLIT)              // 512
#define CHUNKS_PER_BLOCK (COLS_PER_BLOCK / CHUNK) // 16
#define NBLOCKS (32 * JSPLIT)                     // 512 = 2 per CU
#define SWZ(r, b) ((b) ^ (((r) & 7) << 4))
// rows pre-scaled by s, s^2 = 2*log2(e): MFMA acc is already exp2-domain
#define PRESCALE 1.6986436f
#define INV_S2   0.34657359f   // ln2/2 = 1/(2*log2 e): acc -> raw dot

using short8 = __attribute__((ext_vector_type(8))) short;
using f32x4  = __attribute__((ext_vector_type(4))) float;

typedef __attribute__((address_space(1))) const char gchar_t;
typedef __attribute__((address_space(3))) char       lchar_t;

__device__ inline unsigned short f2bf(float x) {
    union { float f; uint32_t u; } a; a.f = x;
    uint32_t r = (a.u + 0x7fff + ((a.u >> 16) & 1)) >> 16;  // RNE
    return (unsigned short)r;
}

// ---------------- kernel 1: interleave + L2-normalize + scale + bf16 --------
__global__ void knorm(const float* __restrict__ z1, const float* __restrict__ z2,
                      unsigned short* __restrict__ Zb, float* __restrict__ den,
                      int* __restrict__ counter) {
    int tid  = threadIdx.x;
    int lane = tid & 63;
    int w    = tid >> 6;
    int row  = blockIdx.x * 4 + w;          // 0..8191
    const float* src = (row & 1) ? z2 : z1;
    int srow = row >> 1;
    float4 v = reinterpret_cast<const float4*>(src + (size_t)srow * D)[lane];
    float ss = v.x*v.x + v.y*v.y + v.z*v.z + v.w*v.w;
    #pragma unroll
    for (int off = 1; off < 64; off <<= 1) ss += __shfl_xor(ss, off);
    float inv = rsqrtf(ss) * PRESCALE;
    ushort4 o;
    o.x = f2bf(v.x * inv); o.y = f2bf(v.y * inv);
    o.z = f2bf(v.z * inv); o.w = f2bf(v.w * inv);
    *reinterpret_cast<ushort4*>(Zb + (size_t)row * D + lane * 4) = o;

    int gid = blockIdx.x * blockDim.x + tid;
    if (gid < N2) den[gid] = 0.f;
    if (gid == 0) *counter = 0;
}

// ------- kernel 2: S rowsums (excl diag) + positive dots + final loss -------
__launch_bounds__(256, 2)
__global__ void kmain(const unsigned short* __restrict__ Zb,
                      float* __restrict__ den, float* __restrict__ pos,
                      int* __restrict__ counter, float* __restrict__ out) {
    __shared__ char tile[2][CHUNK * DB];     // 2 x 16 KB double buffer
    int tid  = threadIdx.x;
    int lane = tid & 63;
    int w    = tid >> 6;                     // 0..3
    int bid  = blockIdx.x;
    int rb   = bid & 31;                     // 32 row-blocks of 256 rows
    int js   = bid >> 5;                     // 16 column splits
    int Rw   = rb * BLK_ROWS + w * WAVE_ROWS;
    int Cbase = js * COLS_PER_BLOCK;
    int l15 = lane & 15, g = lane >> 4;

    const char* Zc = reinterpret_cast<const char*>(Zb);

    // staging geometry: each wave stages 8 rows via 4 DMA ops (2 rows each);
    // global source pre-swizzled so linear LDS dest yields swizzled layout.
    int soff[4];
    #pragma unroll
    for (int k = 0; k < 4; ++k) {
        int r = w*8 + k*2 + (lane >> 5);     // local row 0..31
        int y = (lane & 31) * 16;
        soff[k] = r * DB + SWZ(r, y);
    }
    const size_t cb0 = (size_t)Cbase * DB;

    #define STAGE(bf, coff)                                                          \
        _Pragma("unroll")                                                            \
        for (int k = 0; k < 4; ++k)                                                  \
            __builtin_amdgcn_global_load_lds(                                        \
                (gchar_t*)(Zc + (coff) + soff[k]),                                   \
                (lchar_t*)(&tile[bf][(w*8 + k*2) * DB]), 16, 0, 0);

    STAGE(0, cb0);                           // prologue: chunk 0 -> buf 0 (in flight)

    // A fragments: 4 m-frags x 8 k-steps = 128 VGPRs, loaded via inline asm so
    // they CANNOT be rematerialized/sunk — forced register-resident.
    short8 A[4][8];
    #pragma unroll
    for (int mf = 0; mf < 4; ++mf) {
        uint64_t rowp = (uint64_t)(Zc + (size_t)(Rw + mf*16 + l15) * DB + g*16);
        #pragma unroll
        for (int s = 0; s < 8; ++s) {
            asm volatile("global_load_dwordx4 %0, %1, off"
                         : "=v"(A[mf][s]) : "v"(rowp + (uint64_t)(s*64)));
        }
    }
    asm volatile("s_waitcnt vmcnt(0)" ::: "memory");
    __builtin_amdgcn_sched_barrier(0);       // rule 18: nothing hoists above wait

    float rsum[4][4];
    #pragma unroll
    for (int mf = 0; mf < 4; ++mf)
        #pragma unroll
        for (int r = 0; r < 4; ++r) rsum[mf][r] = 0.f;

    __syncthreads();                         // buf0 staged
    __builtin_amdgcn_sched_barrier(0);
    int buf = 0;

    for (int c = 0; c < CHUNKS_PER_BLOCK; ++c) {
        if (c + 1 < CHUNKS_PER_BLOCK)        // readers of buf^1 flushed last iter
            STAGE(buf ^ 1, cb0 + (size_t)(c + 1) * CHUNK * DB);

        f32x4 acc[4][2];
        #pragma unroll
        for (int mf = 0; mf < 4; ++mf)
            #pragma unroll
            for (int nf = 0; nf < 2; ++nf) acc[mf][nf] = (f32x4){0.f,0.f,0.f,0.f};

        #pragma unroll
        for (int s = 0; s < 8; ++s) {
            int cb = s*64 + g*16;
            int r0 = l15, r1 = 16 + l15;
            short8 B0 = *reinterpret_cast<const short8*>(&tile[buf][r0 * DB + SWZ(r0, cb)]);
            short8 B1 = *reinterpret_cast<const short8*>(&tile[buf][r1 * DB + SWZ(r1, cb)]);
            #pragma unroll
            for (int mf = 0; mf < 4; ++mf) {
                acc[mf][0] = __builtin_amdgcn_mfma_f32_16x16x32_bf16(A[mf][s], B0, acc[mf][0], 0, 0, 0);
                acc[mf][1] = __builtin_amdgcn_mfma_f32_16x16x32_bf16(A[mf][s], B1, acc[mf][1], 0, 0, 0);
            }
        }

        int C0 = Cbase + c * CHUNK;
        #pragma unroll
        for (int mf = 0; mf < 4; ++mf) {
            int Rt = Rw + mf * 16;
            #pragma unroll
            for (int nf = 0; nf < 2; ++nf) {
                int Ct = C0 + nf * 16;
                bool dg = (Ct == Rt);
                if (dg) {
                    #pragma unroll
                    for (int r = 0; r < 4; ++r) {
                        float v = acc[mf][nf][r];        // already exp2-domain
                        float e = exp2f(v);
                        int rl = g * 4 + r;
                        if (l15 == rl) e = 0.f;                       // diagonal
                        if (l15 == (rl ^ 1)) pos[Rt + rl] = v * INV_S2; // raw dot
                        rsum[mf][r] += e;
                    }
                } else {
                    #pragma unroll
                    for (int r = 0; r < 4; ++r)
                        rsum[mf][r] += exp2f(acc[mf][nf][r]);
                }
            }
        }
        __syncthreads();   // drains vmcnt+lgkmcnt then barrier: next STAGE safe
        buf ^= 1;
    }

    // reduce rowsums across the 16 cols held per lane-group, then accumulate
    #pragma unroll
    for (int mf = 0; mf < 4; ++mf) {
        #pragma unroll
        for (int r = 0; r < 4; ++r) {
            float v = rsum[mf][r];
            v += __shfl_xor(v, 1); v += __shfl_xor(v, 2);
            v += __shfl_xor(v, 4); v += __shfl_xor(v, 8);
            if (l15 == 0) atomicAdd(&den[Rw + mf*16 + g*4 + r], v);
        }
    }

    // ---- last block computes the final loss ----
    __shared__ int  amLast;
    __shared__ float red[4];
    __threadfence();                         // den/pos visible device-wide
    __syncthreads();
    if (tid == 0) amLast = (atomicAdd(counter, 1) == NBLOCKS - 1);
    __syncthreads();
    if (!amLast) return;
    __threadfence();                         // acquire

    float s = 0.f;
    for (int i = tid; i < N2; i += 256) {
        float d = __hip_atomic_load(&den[i], __ATOMIC_RELAXED, __HIP_MEMORY_SCOPE_AGENT);
        float p = __hip_atomic_load(&pos[i], __ATOMIC_RELAXED, __HIP_MEMORY_SCOPE_AGENT);
        s += logf(d + 1e-8f) - 2.f * p;
    }
    #pragma unroll
    for (int off = 1; off < 64; off <<= 1) s += __shfl_xor(s, off);
    if (lane == 0) red[w] = s;
    __syncthreads();
    if (tid == 0) {
        float t = 0.f;
        #pragma unroll
        for (int i = 0; i < 4; ++i) t += red[i];
        out[0] = t * (1.f / (float)N2);
    }
}

extern "C" void kernel_launch(void* const* d_in, const int* in_sizes, int n_in,
                              void* d_out, int out_size, void* d_ws, size_t ws_size,
                              hipStream_t stream) {
    const float* z1 = (const float*)d_in[0];
    const float* z2 = (const float*)d_in[1];
    char* ws = (char*)d_ws;
    unsigned short* Zb = (unsigned short*)ws;                       // 4 MB bf16 Z
    float* den = (float*)(ws + (size_t)N2 * DB);                    // 32 KB
    float* pos = (float*)(ws + (size_t)N2 * DB + (size_t)N2 * 4);   // 32 KB
    int* counter = (int*)(ws + (size_t)N2 * DB + (size_t)N2 * 8);

    knorm<<<N2 / 4, 256, 0, stream>>>(z1, z2, Zb, den, counter);
    kmain<<<NBLOCKS, 256, 0, stream>>>(Zb, den, pos, counter, (float*)d_out);
}